// Round 3
// baseline (338.692 us; speedup 1.0000x reference)
//
#include <hip/hip_runtime.h>
#include <hip/hip_bf16.h>

// AtomFeatureEmbedder on MI355X (gfx950).
// Inputs: float32 (+ uid int32). Outputs: float32, concat
// [cl (1,2048,128), plm (1,2048,2048,16)].
// plm dominates: 268.4 MB of f32 stores -> write-BW bound (~43 us floor at
// 6.3 TB/s). ~99.6% of pairs are uid-mismatch -> pure zero stores.
// cl (tiny 2048x390x128 GEMM, ~204 MFLOP) is fused into the same launch.

#define N_ATOMS   2048
#define C_ATOM    128
#define C_PAIR    16
#define CL_ATOMS  8                      // atoms per cl block
#define CL_BLOCKS (N_ATOMS / CL_ATOMS)   // 256
#define KP        392                    // 390 features padded to multiple of 4
#define PLM_BLOCKS N_ATOMS               // one block per l

extern "C" __global__ __launch_bounds__(256)
void atom_embed_kernel(const float* __restrict__ pos,      // [2048,3] f32
                       const float* __restrict__ mask,     // [2048]
                       const float* __restrict__ elem,     // [2048,128]
                       const float* __restrict__ charge,   // [2048]
                       const float* __restrict__ chars,    // [2048,256]
                       const int*   __restrict__ uid,      // [2048] int32
                       const float* __restrict__ Wf,       // [390,128]
                       const float* __restrict__ Woff,     // [3,16]
                       const float* __restrict__ Winv,     // [1,16]
                       const float* __restrict__ Wmask,    // [1,16]
                       float* __restrict__ out)            // cl (262144) then plm
{
    const int tid = threadIdx.x;

    if (blockIdx.x < CL_BLOCKS) {
        // ---------------- cl = feats @ W_feats ----------------
        __shared__ __align__(16) float sf[CL_ATOMS * KP];
        const int atom0 = blockIdx.x * CL_ATOMS;

        // Stage 8 atoms x 390 features into LDS; pad [390..391] with 0.
        for (int idx = tid; idx < CL_ATOMS * KP; idx += 256) {
            const int a = idx / KP;
            const int k = idx - a * KP;
            const int ga = atom0 + a;
            float v = 0.0f;
            if (k < 3)          v = pos[ga * 3 + k];
            else if (k == 3)    v = mask[ga];
            else if (k < 132)   v = elem[ga * 128 + (k - 4)];
            else if (k == 132)  v = charge[ga];
            else if (k < 389)   v = chars[ga * 256 + (k - 133)];
            else if (k == 389)  v = (float)uid[ga];
            sf[idx] = v;
        }
        __syncthreads();

        const int col = tid & 127;
        const int sub = tid >> 7;          // 0 or 1 -> atoms [sub*4, sub*4+4)
        const float* sfa = &sf[sub * 4 * KP];
        float acc[4] = {0.f, 0.f, 0.f, 0.f};

        for (int k0 = 0; k0 < 388; k0 += 4) {
            const float w0 = Wf[(k0 + 0) * 128 + col];
            const float w1 = Wf[(k0 + 1) * 128 + col];
            const float w2 = Wf[(k0 + 2) * 128 + col];
            const float w3 = Wf[(k0 + 3) * 128 + col];
            #pragma unroll
            for (int a = 0; a < 4; a++) {
                const float4 f = *(const float4*)&sfa[a * KP + k0];
                acc[a] += f.x * w0 + f.y * w1 + f.z * w2 + f.w * w3;
            }
        }
        {   // tail: k = 388, 389
            const float w0 = Wf[388 * 128 + col];
            const float w1 = Wf[389 * 128 + col];
            #pragma unroll
            for (int a = 0; a < 4; a++) {
                const float2 f = *(const float2*)&sfa[a * KP + 388];
                acc[a] += f.x * w0 + f.y * w1;
            }
        }
        #pragma unroll
        for (int a = 0; a < 4; a++) {
            const int ga = atom0 + sub * 4 + a;
            out[ga * 128 + col] = acc[a];
        }
    } else {
        // ---------------- plm ----------------
        const int l = blockIdx.x - CL_BLOCKS;
        const float lx = pos[l * 3 + 0];
        const float ly = pos[l * 3 + 1];
        const float lz = pos[l * 3 + 2];
        const int   ul = uid[l];

        // Weights: wave-uniform loads with constant offsets -> scalar regs.
        float wox[16], woy[16], woz[16], wiv[16], wmk[16];
        #pragma unroll
        for (int c = 0; c < 16; c++) {
            wox[c] = Woff[c];
            woy[c] = Woff[16 + c];
            woz[c] = Woff[32 + c];
            wiv[c] = Winv[c];
            wmk[c] = Wmask[c];
        }

        float* plm = out + (size_t)N_ATOMS * C_ATOM;

        #pragma unroll
        for (int k = 0; k < 8; k++) {
            const int m = k * 256 + tid;
            float t[16];
            #pragma unroll
            for (int c = 0; c < 16; c++) t[c] = 0.0f;
            if (uid[m] == ul) {
                const float dx = pos[m * 3 + 0] - lx;
                const float dy = pos[m * 3 + 1] - ly;
                const float dz = pos[m * 3 + 2] - lz;
                const float invd = 1.0f / (1.0f + sqrtf(dx * dx + dy * dy + dz * dz));
                #pragma unroll
                for (int c = 0; c < 16; c++) {
                    t[c] = dx * wox[c] + dy * woy[c] + dz * woz[c]
                         + invd * wiv[c] + wmk[c];
                }
            }
            float4* p = (float4*)(plm + ((size_t)l * N_ATOMS + m) * C_PAIR);
            p[0] = make_float4(t[0],  t[1],  t[2],  t[3]);
            p[1] = make_float4(t[4],  t[5],  t[6],  t[7]);
            p[2] = make_float4(t[8],  t[9],  t[10], t[11]);
            p[3] = make_float4(t[12], t[13], t[14], t[15]);
        }
    }
}

extern "C" void kernel_launch(void* const* d_in, const int* in_sizes, int n_in,
                              void* d_out, int out_size, void* d_ws, size_t ws_size,
                              hipStream_t stream) {
    const float* pos    = (const float*)d_in[0];
    const float* rmask  = (const float*)d_in[1];
    const float* elem   = (const float*)d_in[2];
    const float* charge = (const float*)d_in[3];
    const float* chars  = (const float*)d_in[4];
    const int*   uid    = (const int*)d_in[5];
    const float* Wf     = (const float*)d_in[6];
    const float* Woff   = (const float*)d_in[7];
    const float* Winv   = (const float*)d_in[8];
    const float* Wmask  = (const float*)d_in[9];
    float* out = (float*)d_out;

    dim3 grid(CL_BLOCKS + PLM_BLOCKS);  // cl blocks first so they start early
    atom_embed_kernel<<<grid, 256, 0, stream>>>(
        pos, rmask, elem, charge, chars, uid, Wf, Woff, Winv, Wmask, out);
}

// Round 4
// 312.127 us; speedup vs baseline: 1.0851x; 1.0851x over previous
//
#include <hip/hip_runtime.h>
#include <hip/hip_bf16.h>

// AtomFeatureEmbedder on MI355X (gfx950).
// Inputs: float32 (+ uid int32). Outputs: float32, concat
// [cl (1,2048,128), plm (1,2048,2048,16)].
// plm = 268.4 MB of f32 stores -> write-BW bound (~43 us floor at 6.3 TB/s;
// harness fill kernel demonstrates 6.5 TB/s on this buffer).
// R3 post-mortem: old plm path was ~4x off the floor — 64B-strided 16B stores
// (25% line density per instruction) + VGPR spill from t[16] x 8 unroll and an
// 80-float weight preload. This version: lane i writes float4 i (fully
// contiguous 1KB/wave-instruction), 4 floats live state, weights loaded only
// inside the 0.4%-taken uid-match branch.

#define N_ATOMS   2048
#define C_ATOM    128
#define C_PAIR    16
#define CL_ATOMS  8                      // atoms per cl block
#define CL_BLOCKS (N_ATOMS / CL_ATOMS)   // 256
#define KP        392                    // 390 features padded to multiple of 4
#define PLM_BLOCKS (N_ATOMS * 2)         // 2 blocks per row l -> 4096
#define ROW_F4    (N_ATOMS * C_PAIR / 4) // 8192 float4 per row
#define HALF_F4   (ROW_F4 / 2)           // 4096 float4 per block

extern "C" __global__ __launch_bounds__(256)
void atom_embed_kernel(const float* __restrict__ pos,      // [2048,3] f32
                       const float* __restrict__ mask,     // [2048]
                       const float* __restrict__ elem,     // [2048,128]
                       const float* __restrict__ charge,   // [2048]
                       const float* __restrict__ chars,    // [2048,256]
                       const int*   __restrict__ uid,      // [2048] int32
                       const float* __restrict__ Wf,       // [390,128]
                       const float* __restrict__ Woff,     // [3,16]
                       const float* __restrict__ Winv,     // [1,16]
                       const float* __restrict__ Wmask,    // [1,16]
                       float* __restrict__ out)            // cl (262144) then plm
{
    const int tid = threadIdx.x;

    if (blockIdx.x < CL_BLOCKS) {
        // ---------------- cl = feats @ W_feats ----------------
        __shared__ __align__(16) float sf[CL_ATOMS * KP];
        const int atom0 = blockIdx.x * CL_ATOMS;

        // Stage 8 atoms x 390 features into LDS; pad [390..391] with 0.
        for (int idx = tid; idx < CL_ATOMS * KP; idx += 256) {
            const int a = idx / KP;
            const int k = idx - a * KP;
            const int ga = atom0 + a;
            float v = 0.0f;
            if (k < 3)          v = pos[ga * 3 + k];
            else if (k == 3)    v = mask[ga];
            else if (k < 132)   v = elem[ga * 128 + (k - 4)];
            else if (k == 132)  v = charge[ga];
            else if (k < 389)   v = chars[ga * 256 + (k - 133)];
            else if (k == 389)  v = (float)uid[ga];
            sf[idx] = v;
        }
        __syncthreads();

        const int col = tid & 127;
        const int sub = tid >> 7;          // 0 or 1 -> atoms [sub*4, sub*4+4)
        const float* sfa = &sf[sub * 4 * KP];
        float acc[4] = {0.f, 0.f, 0.f, 0.f};

        for (int k0 = 0; k0 < 388; k0 += 4) {
            const float w0 = Wf[(k0 + 0) * 128 + col];
            const float w1 = Wf[(k0 + 1) * 128 + col];
            const float w2 = Wf[(k0 + 2) * 128 + col];
            const float w3 = Wf[(k0 + 3) * 128 + col];
            #pragma unroll
            for (int a = 0; a < 4; a++) {
                const float4 f = *(const float4*)&sfa[a * KP + k0];
                acc[a] += f.x * w0 + f.y * w1 + f.z * w2 + f.w * w3;
            }
        }
        {   // tail: k = 388, 389
            const float w0 = Wf[388 * 128 + col];
            const float w1 = Wf[389 * 128 + col];
            #pragma unroll
            for (int a = 0; a < 4; a++) {
                const float2 f = *(const float2*)&sfa[a * KP + 388];
                acc[a] += f.x * w0 + f.y * w1;
            }
        }
        #pragma unroll
        for (int a = 0; a < 4; a++) {
            const int ga = atom0 + sub * 4 + a;
            out[ga * 128 + col] = acc[a];
        }
    } else {
        // ---------------- plm ----------------
        const int bb = blockIdx.x - CL_BLOCKS;   // [0, 4096)
        const int l  = bb >> 1;                  // row
        const int f0 = (bb & 1) * HALF_F4;       // float4 base within row

        const float lx = pos[l * 3 + 0];
        const float ly = pos[l * 3 + 1];
        const float lz = pos[l * 3 + 2];
        const int   ul = uid[l];

        float4* row = (float4*)(out + (size_t)N_ATOMS * C_ATOM
                                    + (size_t)l * N_ATOMS * C_PAIR);

        #pragma unroll 4
        for (int j = 0; j < HALF_F4 / 256; j++) {   // 16 iterations
            const int f = f0 + j * 256 + tid;       // float4 index in row
            const int m = f >> 2;                   // pair column
            const int g = f & 3;                    // channel group (4 ch)
            float4 v = make_float4(0.f, 0.f, 0.f, 0.f);
            if (uid[m] == ul) {
                const float dx = pos[m * 3 + 0] - lx;
                const float dy = pos[m * 3 + 1] - ly;
                const float dz = pos[m * 3 + 2] - lz;
                const float invd = 1.0f / (1.0f + sqrtf(dx * dx + dy * dy + dz * dz));
                const float4 wx = *(const float4*)&Woff[4 * g];
                const float4 wy = *(const float4*)&Woff[16 + 4 * g];
                const float4 wz = *(const float4*)&Woff[32 + 4 * g];
                const float4 wi = *(const float4*)&Winv[4 * g];
                const float4 wm = *(const float4*)&Wmask[4 * g];
                v.x = dx * wx.x + dy * wy.x + dz * wz.x + invd * wi.x + wm.x;
                v.y = dx * wx.y + dy * wy.y + dz * wz.y + invd * wi.y + wm.y;
                v.z = dx * wx.z + dy * wy.z + dz * wz.z + invd * wi.z + wm.z;
                v.w = dx * wx.w + dy * wy.w + dz * wz.w + invd * wi.w + wm.w;
            }
            row[f] = v;
        }
    }
}

extern "C" void kernel_launch(void* const* d_in, const int* in_sizes, int n_in,
                              void* d_out, int out_size, void* d_ws, size_t ws_size,
                              hipStream_t stream) {
    const float* pos    = (const float*)d_in[0];
    const float* rmask  = (const float*)d_in[1];
    const float* elem   = (const float*)d_in[2];
    const float* charge = (const float*)d_in[3];
    const float* chars  = (const float*)d_in[4];
    const int*   uid    = (const int*)d_in[5];
    const float* Wf     = (const float*)d_in[6];
    const float* Woff   = (const float*)d_in[7];
    const float* Winv   = (const float*)d_in[8];
    const float* Wmask  = (const float*)d_in[9];
    float* out = (float*)d_out;

    dim3 grid(CL_BLOCKS + PLM_BLOCKS);  // cl blocks first so they start early
    atom_embed_kernel<<<grid, 256, 0, stream>>>(
        pos, rmask, elem, charge, chars, uid, Wf, Woff, Winv, Wmask, out);
}